// Round 5
// baseline (120.120 us; speedup 1.0000x reference)
//
#include <hip/hip_runtime.h>
#include <stdint.h>

#define M_DIM 4096
#define K_DIM 4096
#define N_DIM 4096

typedef int v4i __attribute__((ext_vector_type(4)));
typedef int int32x4 __attribute__((ext_vector_type(4)));

__device__ __forceinline__ void gload_lds16(const void* g, void* l) {
    __builtin_amdgcn_global_load_lds(
        (const __attribute__((address_space(1))) uint32_t*)g,
        (__attribute__((address_space(3))) uint32_t*)l, 16, 0, 0);
}

// ---------------- Pass 1: merged pack (A elementwise + B transpose) ----------------
__global__ void pack_ab_kernel(const int* __restrict__ a, char* __restrict__ a8,
                               const int* __restrict__ b, char* __restrict__ b8t) {
    __shared__ char tile[64][68];  // +4 pad (B branch only)
    if (blockIdx.x < 2048) {
        int idx = blockIdx.x * 256 + threadIdx.x;
        const int stride = 2048 * 256;
        const int total4 = M_DIM * K_DIM / 4;
        for (int i = idx; i < total4; i += stride) {
            int32x4 v = ((const int32x4*)a)[i];
            uint32_t p = (uint32_t)(v.x & 0xff) | ((uint32_t)(v.y & 0xff) << 8) |
                         ((uint32_t)(v.z & 0xff) << 16) | ((uint32_t)(v.w & 0xff) << 24);
            ((uint32_t*)a8)[i] = p;
        }
    } else {
        int bid2 = blockIdx.x - 2048;        // 0..4095
        int n0 = (bid2 & 63) * 64;
        int k0 = (bid2 >> 6) * 64;
        int tx = threadIdx.x & 63;
        int ty = threadIdx.x >> 6;  // 0..3
#pragma unroll
        for (int kk = 0; kk < 64; kk += 4) {
            tile[kk + ty][tx] = (char)b[(size_t)(k0 + kk + ty) * N_DIM + n0 + tx];
        }
        __syncthreads();
        int td = threadIdx.x & 15;  // dword index along k (0..15)
        int tn = threadIdx.x >> 4;  // 0..15
#pragma unroll
        for (int nn0 = 0; nn0 < 64; nn0 += 16) {
            int nn = nn0 + tn;
            uint32_t p = (uint32_t)(uint8_t)tile[td * 4 + 0][nn] |
                         ((uint32_t)(uint8_t)tile[td * 4 + 1][nn] << 8) |
                         ((uint32_t)(uint8_t)tile[td * 4 + 2][nn] << 16) |
                         ((uint32_t)(uint8_t)tile[td * 4 + 3][nn] << 24);
            *(uint32_t*)&b8t[(size_t)(n0 + nn) * K_DIM + k0 + td * 4] = p;
        }
    }
}

// ---------------- Pass 2: i8 GEMM, 128x128 tile, TLP-first (4 blocks/CU) ----------------
// BM=BN=128, BK=64. 256 threads = 4 waves, ONE WAVE PER SIMD -> with 4 blocks/CU
// each SIMD hosts 4 waves from 4 INDEPENDENT blocks (independent progress; when one
// block barriers/drains, the other 3 keep the matrix pipe fed).
// LDS 32 KiB: 2 buffers x {A 8 KiB (128 rows x 64B), B 8 KiB}.
// Conflict-free involution layout: chunk c of row r at slot c ^ ((r>>1)&3),
// applied via pre-swizzled global source (linear DMA dest) + swizzled read slot.
// Window kt: {8 ds_read -> 16 MFMA -> BAR -> stage(kt+2 -> buf[kt&1], just vacated)
//             -> vmcnt(4) (drains S(kt+1), leaves S(kt+2)) -> BAR}.
// No vmcnt(0) in the loop; last two windows peeled (vm0 once).
#define BM 128
#define BN 128
#define BK 64
#define KTILES (K_DIM / BK)   // 64

#define BAR __builtin_amdgcn_s_barrier()
#define WAIT_VM4 asm volatile("s_waitcnt vmcnt(4)" ::: "memory")
#define WAIT_VM0 asm volatile("s_waitcnt vmcnt(0)" ::: "memory")

#define MM16(AF, BF)                                                                    \
    __builtin_amdgcn_s_setprio(1);                                                      \
    _Pragma("unroll") for (int i_ = 0; i_ < 4; ++i_)                                    \
    _Pragma("unroll") for (int j_ = 0; j_ < 4; ++j_)                                    \
        acc[i_][j_] =                                                                   \
            __builtin_amdgcn_mfma_i32_16x16x64_i8(AF[i_], BF[j_], acc[i_][j_], 0, 0, 0);\
    __builtin_amdgcn_s_setprio(0);

__global__ __launch_bounds__(256, 4) void gemm_i8_tlp(const char* __restrict__ A8,
                                                      const char* __restrict__ B8T,
                                                      const float* __restrict__ scale,
                                                      float* __restrict__ out) {
    __shared__ char lds[32768];

    int tid = threadIdx.x;
    int wave = tid >> 6;   // 0..3
    int lane = tid & 63;
    int wr = wave >> 1;    // 0..1 -> 64 M-rows
    int wc = wave & 1;     // 0..1 -> 64 N-cols
    int l15 = lane & 15;

    // XCD-bijective swizzle (grid = 1024, 1024 % 8 == 0)
    int bid = blockIdx.x;
    int swz = (bid & 7) * 128 + (bid >> 3);
    int bm = swz >> 5;  // 0..31
    int bn = swz & 31;  // 0..31

    // staging: per-thread pre-swizzled global source; linear LDS dest.
    // sweep r in {0,1}: row = r*64 + (tid>>2); chunk = (tid&3) ^ ((tid>>3)&3)
    int rA = tid >> 2;                                 // 0..63
    int cc = ((tid & 3) ^ ((tid >> 3) & 3)) << 4;
    const char* aSrc = A8 + (size_t)(bm * BM + rA) * K_DIM + cc;
    const char* bSrc = B8T + (size_t)(bn * BN + rA) * K_DIM + cc;

    // fragment read addressing (swizzled slot; 2-way max per 16-lane group = free)
    int slot = (((lane >> 4) ^ ((lane >> 1) & 3)) << 4);
    int aOff = wr * 4096 + l15 * 64 + slot;            // + buf + i*1024
    int bOff = 8192 + wc * 4096 + l15 * 64 + slot;     // + buf + j*1024

    v4i acc[4][4];
#pragma unroll
    for (int i = 0; i < 4; ++i)
#pragma unroll
        for (int j = 0; j < 4; ++j) acc[i][j] = (v4i){0, 0, 0, 0};

    // stage one K-tile (A 8KB + B 8KB) into buffer bo: 4 gloads/thread
    auto stage = [&](int kt, int bo) {
        const char* sa = aSrc + (size_t)kt * BK;
        const char* sb = bSrc + (size_t)kt * BK;
        char* da = (char*)lds + bo + wave * 1024;
        char* db = da + 8192;
        gload_lds16(sa, da);
        gload_lds16(sa + (size_t)64 * K_DIM, da + 4096);
        gload_lds16(sb, db);
        gload_lds16(sb + (size_t)64 * K_DIM, db + 4096);
    };

    // ---- prologue: S(0)->buf0, S(1)->buf1 ----
    stage(0, 0);
    stage(1, 16384);
    WAIT_VM4;   // S(0) landed; S(1) in flight
    BAR;

    v4i aF[4], bF[4];

    for (int kt = 0; kt < KTILES - 2; ++kt) {
        int cur = (kt & 1) << 14;
        // read + compute current tile
#pragma unroll
        for (int i = 0; i < 4; ++i) aF[i] = *(const v4i*)(lds + cur + aOff + i * 1024);
#pragma unroll
        for (int j = 0; j < 4; ++j) bF[j] = *(const v4i*)(lds + cur + bOff + j * 1024);
        MM16(aF, bF);
        BAR;  // all waves done reading buf[cur] (MFMA deps forced lgkm drain)
        stage(kt + 2, cur);  // refill vacated buffer
        WAIT_VM4;            // drains S(kt+1) (next window's data); S(kt+2) in flight
        BAR;
    }

    // ---- peeled tail: kt = KTILES-2, KTILES-1 ----
    {
        int cur = ((KTILES - 2) & 1) << 14;
#pragma unroll
        for (int i = 0; i < 4; ++i) aF[i] = *(const v4i*)(lds + cur + aOff + i * 1024);
#pragma unroll
        for (int j = 0; j < 4; ++j) bF[j] = *(const v4i*)(lds + cur + bOff + j * 1024);
        MM16(aF, bF);
        WAIT_VM0;  // S(KTILES-1) landed
        BAR;
        cur ^= 16384;
#pragma unroll
        for (int i = 0; i < 4; ++i) aF[i] = *(const v4i*)(lds + cur + aOff + i * 1024);
#pragma unroll
        for (int j = 0; j < 4; ++j) bF[j] = *(const v4i*)(lds + cur + bOff + j * 1024);
        MM16(aF, bF);
    }

    // ---- C write: out[row][col] = acc * scale[col] ----
    size_t orow0 = (size_t)bm * BM + wr * 64 + (lane >> 4) * 4;
    int ocol0 = bn * BN + wc * 64 + l15;
#pragma unroll
    for (int j = 0; j < 4; ++j) {
        int col = ocol0 + j * 16;
        float s = scale[col];
#pragma unroll
        for (int i = 0; i < 4; ++i) {
            size_t row = orow0 + (size_t)i * 16;
#pragma unroll
            for (int r = 0; r < 4; ++r) {
                out[(row + r) * N_DIM + col] = (float)acc[i][j][r] * s;
            }
        }
    }
}

// ---------------- Fallback: fused pack GEMM (no workspace needed) ----------------
#define FBM 128
#define FBN 128
#define FBK 64

__global__ __launch_bounds__(256) void gemm_i8_fused_kernel(const int* __restrict__ a,
                                                            const int* __restrict__ b,
                                                            const float* __restrict__ scale,
                                                            float* __restrict__ out) {
    __shared__ char As[FBM * FBK];
    __shared__ char Bs[FBN * FBK];

    int tid = threadIdx.x;
    int wave = tid >> 6;
    int lane = tid & 63;

    int nwg = gridDim.x;
    int cpx = nwg >> 3;
    int bid = blockIdx.x;
    int swz = (bid & 7) * cpx + (bid >> 3);
    int bm = swz >> 5;
    int bn = swz & 31;

    int f0 = tid * 16;
    int m0 = f0 >> 6;
    int k0 = f0 & 63;

    int nn = tid & 127;
    int kh = tid >> 7;  // 0..1

    int wr = wave >> 1;
    int wc = wave & 1;
    int lrow = lane & 15;
    int kgrp = (lane >> 4) * 16;

    v4i acc[4][4];
#pragma unroll
    for (int i = 0; i < 4; ++i)
#pragma unroll
        for (int j = 0; j < 4; ++j) acc[i][j] = (v4i){0, 0, 0, 0};

    const int kTiles = K_DIM / FBK;
    for (int kt = 0; kt < kTiles; ++kt) {
        __syncthreads();
#pragma unroll
        for (int r = 0; r < 2; ++r) {
            const int* src = a + (size_t)(bm * FBM + m0 + r * 64) * K_DIM + kt * FBK + k0;
            uint32_t pk[4];
#pragma unroll
            for (int q = 0; q < 4; ++q) {
                int32x4 v = *(const int32x4*)(src + q * 4);
                pk[q] = (uint32_t)(v.x & 0xff) | ((uint32_t)(v.y & 0xff) << 8) |
                        ((uint32_t)(v.z & 0xff) << 16) | ((uint32_t)(v.w & 0xff) << 24);
            }
            *(v4i*)&As[f0 + r * 4096] = (v4i){(int)pk[0], (int)pk[1], (int)pk[2], (int)pk[3]};
        }
#pragma unroll
        for (int d = 0; d < 8; ++d) {
            uint32_t p = 0;
#pragma unroll
            for (int i = 0; i < 4; ++i) {
                int kk = kt * FBK + kh * 32 + d * 4 + i;
                p |= (uint32_t)(b[(size_t)kk * N_DIM + bn * FBN + nn] & 0xff) << (8 * i);
            }
            *(uint32_t*)&Bs[nn * 64 + kh * 32 + d * 4] = p;
        }
        __syncthreads();

        v4i aF[4], bF[4];
#pragma unroll
        for (int i = 0; i < 4; ++i)
            aF[i] = *(const v4i*)&As[(wr * 64 + i * 16 + lrow) * FBK + kgrp];
#pragma unroll
        for (int j = 0; j < 4; ++j)
            bF[j] = *(const v4i*)&Bs[(wc * 64 + j * 16 + lrow) * FBK + kgrp];
#pragma unroll
        for (int i = 0; i < 4; ++i)
#pragma unroll
            for (int j = 0; j < 4; ++j)
                acc[i][j] = __builtin_amdgcn_mfma_i32_16x16x64_i8(aF[i], bF[j], acc[i][j], 0, 0, 0);
    }

    size_t orow0 = (size_t)bm * FBM + wr * 64;
    int ocol0 = bn * FBN + wc * 64;
#pragma unroll
    for (int j = 0; j < 4; ++j) {
        int col = ocol0 + j * 16 + lrow;
        float s = scale[col];
#pragma unroll
        for (int i = 0; i < 4; ++i) {
            size_t row = orow0 + i * 16 + (lane >> 4) * 4;
#pragma unroll
            for (int r = 0; r < 4; ++r) {
                out[(row + r) * N_DIM + col] = (float)acc[i][j][r] * s;
            }
        }
    }
}

extern "C" void kernel_launch(void* const* d_in, const int* in_sizes, int n_in,
                              void* d_out, int out_size, void* d_ws, size_t ws_size,
                              hipStream_t stream) {
    const int* a = (const int*)d_in[0];
    const int* b = (const int*)d_in[1];
    const float* scale = (const float*)d_in[2];
    float* out = (float*)d_out;

    size_t need = (size_t)M_DIM * K_DIM + (size_t)K_DIM * N_DIM;  // 32 MiB int8
    if (ws_size >= need) {
        char* a8 = (char*)d_ws;
        char* b8t = a8 + (size_t)M_DIM * K_DIM;
        pack_ab_kernel<<<2048 + 4096, 256, 0, stream>>>(a, a8, b, b8t);
        gemm_i8_tlp<<<1024, 256, 0, stream>>>(a8, b8t, scale, out);
    } else {
        gemm_i8_fused_kernel<<<1024, 256, 0, stream>>>(a, b, scale, out);
    }
}

// Round 6
// 92.574 us; speedup vs baseline: 1.2976x; 1.2976x over previous
//
#include <hip/hip_runtime.h>
#include <stdint.h>

#define M_DIM 4096
#define K_DIM 4096
#define N_DIM 4096

typedef int v4i __attribute__((ext_vector_type(4)));
typedef int int32x4 __attribute__((ext_vector_type(4)));

__device__ __forceinline__ void gload_lds16(const void* g, void* l) {
    __builtin_amdgcn_global_load_lds(
        (const __attribute__((address_space(1))) uint32_t*)g,
        (__attribute__((address_space(3))) uint32_t*)l, 16, 0, 0);
}

// ---------------- Pass 1: merged pack (A elementwise + B transpose) ----------------
__global__ void pack_ab_kernel(const int* __restrict__ a, char* __restrict__ a8,
                               const int* __restrict__ b, char* __restrict__ b8t) {
    __shared__ char tile[64][68];  // +4 pad (B branch only)
    if (blockIdx.x < 2048) {
        int idx = blockIdx.x * 256 + threadIdx.x;
        const int stride = 2048 * 256;
        const int total4 = M_DIM * K_DIM / 4;
        for (int i = idx; i < total4; i += stride) {
            int32x4 v = ((const int32x4*)a)[i];
            uint32_t p = (uint32_t)(v.x & 0xff) | ((uint32_t)(v.y & 0xff) << 8) |
                         ((uint32_t)(v.z & 0xff) << 16) | ((uint32_t)(v.w & 0xff) << 24);
            ((uint32_t*)a8)[i] = p;
        }
    } else {
        int bid2 = blockIdx.x - 2048;        // 0..4095
        int n0 = (bid2 & 63) * 64;
        int k0 = (bid2 >> 6) * 64;
        int tx = threadIdx.x & 63;
        int ty = threadIdx.x >> 6;  // 0..3
#pragma unroll
        for (int kk = 0; kk < 64; kk += 4) {
            tile[kk + ty][tx] = (char)b[(size_t)(k0 + kk + ty) * N_DIM + n0 + tx];
        }
        __syncthreads();
        int td = threadIdx.x & 15;  // dword index along k (0..15)
        int tn = threadIdx.x >> 4;  // 0..15
#pragma unroll
        for (int nn0 = 0; nn0 < 64; nn0 += 16) {
            int nn = nn0 + tn;
            uint32_t p = (uint32_t)(uint8_t)tile[td * 4 + 0][nn] |
                         ((uint32_t)(uint8_t)tile[td * 4 + 1][nn] << 8) |
                         ((uint32_t)(uint8_t)tile[td * 4 + 2][nn] << 16) |
                         ((uint32_t)(uint8_t)tile[td * 4 + 3][nn] << 24);
            *(uint32_t*)&b8t[(size_t)(n0 + nn) * K_DIM + k0 + td * 4] = p;
        }
    }
}

// ---------------- Pass 2: i8 GEMM, 256x256, register ping-pong (R6) ----------------
// BM=BN=256, window BK=64. 8 waves (2Mx4N), 512 threads.
// LDS 96 KiB: 3-buffer ring, each 32 KiB {A 16K (256 rows x 64B), B 16K}.
// Conflict-free involution: chunk c of row r at slot c ^ ((r>>1)&3), applied via
// pre-swizzled global source (linear DMA dest) + swizzled read slot.
// Window w (invariant: cur=buf[w%3], nxt=buf[(w+1)%3], stg=buf[(w+2)%3]):
//   stage S(w+2)->stg (4 gload_lds16/thread)      [outstanding: S(w+1)+S(w+2)=8]
//   vmcnt(4)   -- own S(w+1) drained
//   BAR        -- publishes S(w+1) to all; stg vacancy guaranteed by prior lgkm0+BAR
//   12 ds_read frags(w+1) -> alternate regset (from nxt)
//   32 MFMA on current regset (independent of the reads -> pipes overlap)
//   lgkmcnt(0) -- drain own reads (cheap: had full MFMA cluster to finish)
// One barrier per window; vmcnt never 0 in the loop; last 2 windows peeled.
#define BM 256
#define BN 256
#define KTILES (K_DIM / 64)   // 64 windows of BK=64

#define BAR __builtin_amdgcn_s_barrier()
#define WAIT_VM4 asm volatile("s_waitcnt vmcnt(4)" ::: "memory")
#define WAIT_VM0 asm volatile("s_waitcnt vmcnt(0)" ::: "memory")
#define WAIT_LGKM0 asm volatile("s_waitcnt lgkmcnt(0)" ::: "memory")

#define RD_FRAGS(RA, RB)                                                                \
    _Pragma("unroll") for (int i_ = 0; i_ < 8; ++i_)                                    \
        RA[i_] = *(const v4i*)(lds + nxt + aOff + i_ * 1024);                           \
    _Pragma("unroll") for (int j_ = 0; j_ < 4; ++j_)                                    \
        RB[j_] = *(const v4i*)(lds + nxt + bOff + j_ * 1024);

#define SGB_HINT                                                                        \
    _Pragma("unroll") for (int g_ = 0; g_ < 12; ++g_) {                                 \
        __builtin_amdgcn_sched_group_barrier(0x100, 1, 0); /* 1 DS_READ */              \
        __builtin_amdgcn_sched_group_barrier(0x008, 2, 0); /* 2 MFMA */                 \
    }                                                                                   \
    __builtin_amdgcn_sched_group_barrier(0x008, 8, 0);

#define MFMA32(AF, BF)                                                                  \
    __builtin_amdgcn_s_setprio(1);                                                      \
    _Pragma("unroll") for (int i_ = 0; i_ < 8; ++i_)                                    \
    _Pragma("unroll") for (int j_ = 0; j_ < 4; ++j_)                                    \
        acc[i_][j_] = __builtin_amdgcn_mfma_i32_16x16x64_i8(AF[i_], BF[j_],             \
                                                            acc[i_][j_], 0, 0, 0);     \
    __builtin_amdgcn_s_setprio(0);

#define WINDOW(w, RA, RB, MA, MB)                                                       \
    {                                                                                   \
        stage((w) + 2, stg);                                                            \
        WAIT_VM4;                                                                       \
        BAR;                                                                            \
        RD_FRAGS(RA, RB);                                                               \
        SGB_HINT;                                                                       \
        MFMA32(MA, MB);                                                                 \
        WAIT_LGKM0;                                                                     \
        int t_ = cur; cur = nxt; nxt = stg; stg = t_;                                   \
    }

__global__ __launch_bounds__(512, 2) void gemm_i8_pp(const char* __restrict__ A8,
                                                     const char* __restrict__ B8T,
                                                     const float* __restrict__ scale,
                                                     float* __restrict__ out) {
    __shared__ char lds[98304];

    int tid = threadIdx.x;
    int wave = tid >> 6;
    int lane = tid & 63;
    int wr = wave >> 2;  // 0..1 -> 128 M-rows
    int wc = wave & 3;   // 0..3 -> 64 N-cols
    int l15 = lane & 15;

    // XCD-bijective swizzle (grid = 256, 256 % 8 == 0)
    int bid = blockIdx.x;
    int swz = (bid & 7) * 32 + (bid >> 3);
    int bm = swz >> 4;  // 0..15
    int bn = swz & 15;

    // staging geometry: per-thread pre-swizzled global source; linear LDS dest
    int rA = tid >> 2;                                 // row 0..127 (+128 for 2nd gload)
    int cc = ((tid & 3) ^ ((tid >> 3) & 3)) << 4;      // pre-swizzled 16B chunk in 64B row
    const char* aSrc = A8 + (size_t)(bm * BM + rA) * K_DIM + cc;
    const char* bSrc = B8T + (size_t)(bn * BN + rA) * K_DIM + cc;

    // fragment read addressing (swizzled slot; 2-way max per 16-lane group = free)
    int slot = (((lane >> 4) ^ ((lane >> 1) & 3)) << 4);
    int aOff = wr * 8192 + l15 * 64 + slot;            // + buf + i*1024
    int bOff = 16384 + wc * 4096 + l15 * 64 + slot;    // + buf + j*1024

    v4i acc[8][4];
#pragma unroll
    for (int i = 0; i < 8; ++i)
#pragma unroll
        for (int j = 0; j < 4; ++j) acc[i][j] = (v4i){0, 0, 0, 0};

    // stage one BK=64 window (A 16KB + B 16KB) into buffer bo: 4 gloads/thread
    auto stage = [&](int w, int bo) {
        const char* sa = aSrc + (size_t)w * 64;
        const char* sb = bSrc + (size_t)w * 64;
        char* da = (char*)lds + bo + wave * 1024;
        char* db = da + 16384;
        gload_lds16(sa, da);
        gload_lds16(sa + (size_t)128 * K_DIM, da + 8192);
        gload_lds16(sb, db);
        gload_lds16(sb + (size_t)128 * K_DIM, db + 8192);
    };

    // ---- prologue: S(0)->buf0, S(1)->buf1; read frags(0) ----
    stage(0, 0);
    stage(1, 32768);
    WAIT_VM4;  // S(0) landed; S(1) in flight
    BAR;

    int cur = 0, nxt = 32768, stg = 65536;
    v4i pA[8], pB[4], qA[8], qB[4];
    {
        // read frags(0) from buf0 (note: uses cur, not nxt)
#pragma unroll
        for (int i = 0; i < 8; ++i) pA[i] = *(const v4i*)(lds + cur + aOff + i * 1024);
#pragma unroll
        for (int j = 0; j < 4; ++j) pB[j] = *(const v4i*)(lds + cur + bOff + j * 1024);
    }

    // ---- main loop: windows 0..61 (all full) ----
    for (int kt = 0; kt < KTILES - 2; kt += 2) {
        WINDOW(kt, qA, qB, pA, pB);       // read frags(kt+1)->q, compute frags(kt) from p
        WINDOW(kt + 1, pA, pB, qA, qB);   // read frags(kt+2)->p, compute frags(kt+1) from q
    }

    // ---- peeled window 62: no stage; drain S(63); read frags(63)->q; compute p ----
    WAIT_VM0;
    BAR;
    RD_FRAGS(qA, qB);
    MFMA32(pA, pB);
    // ---- peeled window 63: compute q (compiler inserts lgkm wait) ----
    MFMA32(qA, qB);

    // ---- C write: out[row][col] = acc * scale[col] ----
    size_t orow0 = (size_t)bm * BM + wr * 128 + (lane >> 4) * 4;
    int ocol0 = bn * BN + wc * 64 + l15;
#pragma unroll
    for (int j = 0; j < 4; ++j) {
        int col = ocol0 + j * 16;
        float s = scale[col];
#pragma unroll
        for (int i = 0; i < 8; ++i) {
            size_t row = orow0 + (size_t)i * 16;
#pragma unroll
            for (int r = 0; r < 4; ++r) {
                out[(row + r) * N_DIM + col] = (float)acc[i][j][r] * s;
            }
        }
    }
}

// ---------------- Fallback: fused pack GEMM (no workspace needed) ----------------
#define FBM 128
#define FBN 128
#define FBK 64

__global__ __launch_bounds__(256) void gemm_i8_fused_kernel(const int* __restrict__ a,
                                                            const int* __restrict__ b,
                                                            const float* __restrict__ scale,
                                                            float* __restrict__ out) {
    __shared__ char As[FBM * FBK];
    __shared__ char Bs[FBN * FBK];

    int tid = threadIdx.x;
    int wave = tid >> 6;
    int lane = tid & 63;

    int nwg = gridDim.x;
    int cpx = nwg >> 3;
    int bid = blockIdx.x;
    int swz = (bid & 7) * cpx + (bid >> 3);
    int bm = swz >> 5;
    int bn = swz & 31;

    int f0 = tid * 16;
    int m0 = f0 >> 6;
    int k0 = f0 & 63;

    int nn = tid & 127;
    int kh = tid >> 7;  // 0..1

    int wr = wave >> 1;
    int wc = wave & 1;
    int lrow = lane & 15;
    int kgrp = (lane >> 4) * 16;

    v4i acc[4][4];
#pragma unroll
    for (int i = 0; i < 4; ++i)
#pragma unroll
        for (int j = 0; j < 4; ++j) acc[i][j] = (v4i){0, 0, 0, 0};

    const int kTiles = K_DIM / FBK;
    for (int kt = 0; kt < kTiles; ++kt) {
        __syncthreads();
#pragma unroll
        for (int r = 0; r < 2; ++r) {
            const int* src = a + (size_t)(bm * FBM + m0 + r * 64) * K_DIM + kt * FBK + k0;
            uint32_t pk[4];
#pragma unroll
            for (int q = 0; q < 4; ++q) {
                int32x4 v = *(const int32x4*)(src + q * 4);
                pk[q] = (uint32_t)(v.x & 0xff) | ((uint32_t)(v.y & 0xff) << 8) |
                        ((uint32_t)(v.z & 0xff) << 16) | ((uint32_t)(v.w & 0xff) << 24);
            }
            *(v4i*)&As[f0 + r * 4096] = (v4i){(int)pk[0], (int)pk[1], (int)pk[2], (int)pk[3]};
        }
#pragma unroll
        for (int d = 0; d < 8; ++d) {
            uint32_t p = 0;
#pragma unroll
            for (int i = 0; i < 4; ++i) {
                int kk = kt * FBK + kh * 32 + d * 4 + i;
                p |= (uint32_t)(b[(size_t)kk * N_DIM + bn * FBN + nn] & 0xff) << (8 * i);
            }
            *(uint32_t*)&Bs[nn * 64 + kh * 32 + d * 4] = p;
        }
        __syncthreads();

        v4i aF[4], bF[4];
#pragma unroll
        for (int i = 0; i < 4; ++i)
            aF[i] = *(const v4i*)&As[(wr * 64 + i * 16 + lrow) * FBK + kgrp];
#pragma unroll
        for (int j = 0; j < 4; ++j)
            bF[j] = *(const v4i*)&Bs[(wc * 64 + j * 16 + lrow) * FBK + kgrp];
#pragma unroll
        for (int i = 0; i < 4; ++i)
#pragma unroll
            for (int j = 0; j < 4; ++j)
                acc[i][j] = __builtin_amdgcn_mfma_i32_16x16x64_i8(aF[i], bF[j], acc[i][j], 0, 0, 0);
    }

    size_t orow0 = (size_t)bm * FBM + wr * 64;
    int ocol0 = bn * FBN + wc * 64;
#pragma unroll
    for (int j = 0; j < 4; ++j) {
        int col = ocol0 + j * 16 + lrow;
        float s = scale[col];
#pragma unroll
        for (int i = 0; i < 4; ++i) {
            size_t row = orow0 + i * 16 + (lane >> 4) * 4;
#pragma unroll
            for (int r = 0; r < 4; ++r) {
                out[(row + r) * N_DIM + col] = (float)acc[i][j][r] * s;
            }
        }
    }
}

extern "C" void kernel_launch(void* const* d_in, const int* in_sizes, int n_in,
                              void* d_out, int out_size, void* d_ws, size_t ws_size,
                              hipStream_t stream) {
    const int* a = (const int*)d_in[0];
    const int* b = (const int*)d_in[1];
    const float* scale = (const float*)d_in[2];
    float* out = (float*)d_out;

    size_t need = (size_t)M_DIM * K_DIM + (size_t)K_DIM * N_DIM;  // 32 MiB int8
    if (ws_size >= need) {
        char* a8 = (char*)d_ws;
        char* b8t = a8 + (size_t)M_DIM * K_DIM;
        pack_ab_kernel<<<2048 + 4096, 256, 0, stream>>>(a, a8, b, b8t);
        gemm_i8_pp<<<256, 512, 0, stream>>>(a8, b8t, scale, out);
    } else {
        gemm_i8_fused_kernel<<<1024, 256, 0, stream>>>(a, b, scale, out);
    }
}